// Round 1
// baseline (3854.676 us; speedup 1.0000x reference)
//
#include <hip/hip_runtime.h>

#define E_EDGES 1600000
#define NNODES  50000
#define HID     128
#define NRAD    6
#define OE      256

// ---------------------------------------------------------------------------
// Edge stage: e = (rbf @ W_rbf^T) * x, scatter-add into h[NNODES][HID]
// 32 lanes per edge, 4 channels per lane (float4). W_rbf rows live in
// registers (fixed per lane across the grid-stride loop).
// ---------------------------------------------------------------------------
__global__ __launch_bounds__(256) void edge_scatter(
    const float* __restrict__ x, const float* __restrict__ rbf,
    const int* __restrict__ idx, const float* __restrict__ W_rbf,
    float* __restrict__ h)
{
    const int tid = threadIdx.x;
    const int c4 = tid & 31;           // channel group 0..31 -> channels c4*4..c4*4+3
    const int eslot = tid >> 5;        // 0..7 edge slot in block

    float w[4][NRAD];
#pragma unroll
    for (int j = 0; j < 4; ++j)
#pragma unroll
        for (int r = 0; r < NRAD; ++r)
            w[j][r] = W_rbf[(c4 * 4 + j) * NRAD + r];

    const int stride = gridDim.x * 8;
    for (int e = blockIdx.x * 8 + eslot; e < E_EDGES; e += stride) {
        const int node = idx[e];
        const float* rp = rbf + (size_t)e * NRAD;
        const float r0 = rp[0], r1 = rp[1], r2 = rp[2];
        const float r3 = rp[3], r4 = rp[4], r5 = rp[5];
        const float4 xv = *(const float4*)(x + (size_t)e * HID + c4 * 4);
        float* hp = h + (size_t)node * HID + c4 * 4;
        const float xs[4] = {xv.x, xv.y, xv.z, xv.w};
#pragma unroll
        for (int j = 0; j < 4; ++j) {
            const float coeff = w[j][0] * r0 + w[j][1] * r1 + w[j][2] * r2
                              + w[j][3] * r3 + w[j][4] * r4 + w[j][5] * r5;
            unsafeAtomicAdd(hp + j, coeff * xs[j]);
        }
    }
}

// ---------------------------------------------------------------------------
// C[M,256] = A[M,K] @ B[256,K]^T (+bias, relu).  Torch Linear convention.
// BM=64, BN=128, BK=16; 256 threads, 4x8 micro-tile per thread.
// ---------------------------------------------------------------------------
template <bool RELU>
__global__ __launch_bounds__(256) void gemm_bt(
    const float* __restrict__ A, const float* __restrict__ B,
    const float* __restrict__ bias, float* __restrict__ C,
    int M, int K)
{
    constexpr int BM = 64, BN = 128, BK = 16;
    __shared__ float As[BK][BM + 4];
    __shared__ float Bs[BK][BN + 4];

    const int tid = threadIdx.x;
    const int m0 = blockIdx.y * BM;
    const int n0 = blockIdx.x * BN;
    const int tm = (tid & 15) * 4;   // 0..60
    const int tn = (tid >> 4) * 8;   // 0..120

    const int lrow = tid >> 2;       // 0..63
    const int lk   = (tid & 3) * 4;  // 0,4,8,12

    float acc[4][8] = {};

    for (int k0 = 0; k0 < K; k0 += BK) {
        // A tile: 64 rows x 16 k, one float4 per thread, stored k-major
        {
            int row = m0 + lrow;
            row = row < M ? row : M - 1;     // clamp (stores are guarded)
            const float4 v = *(const float4*)(A + (size_t)row * K + k0 + lk);
            As[lk + 0][lrow] = v.x; As[lk + 1][lrow] = v.y;
            As[lk + 2][lrow] = v.z; As[lk + 3][lrow] = v.w;
        }
        // B tile: 128 rows x 16 k, two float4 per thread
#pragma unroll
        for (int half = 0; half < 2; ++half) {
            const int n = n0 + lrow + half * 64;
            const float4 v = *(const float4*)(B + (size_t)n * K + k0 + lk);
            Bs[lk + 0][lrow + half * 64] = v.x;
            Bs[lk + 1][lrow + half * 64] = v.y;
            Bs[lk + 2][lrow + half * 64] = v.z;
            Bs[lk + 3][lrow + half * 64] = v.w;
        }
        __syncthreads();

#pragma unroll
        for (int k = 0; k < BK; ++k) {
            const float4 a  = *(const float4*)&As[k][tm];
            const float4 b0 = *(const float4*)&Bs[k][tn];
            const float4 b1 = *(const float4*)&Bs[k][tn + 4];
            const float av[4] = {a.x, a.y, a.z, a.w};
            const float bv[8] = {b0.x, b0.y, b0.z, b0.w, b1.x, b1.y, b1.z, b1.w};
#pragma unroll
            for (int r = 0; r < 4; ++r)
#pragma unroll
                for (int c = 0; c < 8; ++c)
                    acc[r][c] += av[r] * bv[c];
        }
        __syncthreads();
    }

    float bvals[8];
#pragma unroll
    for (int c = 0; c < 8; ++c)
        bvals[c] = bias ? bias[n0 + tn + c] : 0.0f;

#pragma unroll
    for (int r = 0; r < 4; ++r) {
        const int m = m0 + tm + r;
        if (m >= M) continue;
        float o[8];
#pragma unroll
        for (int c = 0; c < 8; ++c) {
            float v = acc[r][c] + bvals[c];
            if (RELU) v = fmaxf(v, 0.0f);
            o[c] = v;
        }
        float4* cp = (float4*)(C + (size_t)m * OE + n0 + tn);
        cp[0] = make_float4(o[0], o[1], o[2], o[3]);
        cp[1] = make_float4(o[4], o[5], o[6], o[7]);
    }
}

// ---------------------------------------------------------------------------
// out[n] = dot(h[n][:256], W_out[:256]).  One wave per node, 4 floats/lane.
// ---------------------------------------------------------------------------
__global__ __launch_bounds__(256) void out_proj(
    const float* __restrict__ h, const float* __restrict__ Wout,
    float* __restrict__ out)
{
    const int lane = threadIdx.x & 63;
    const int wave = threadIdx.x >> 6;
    const int node = blockIdx.x * 4 + wave;
    if (node >= NNODES) return;
    const float4 hv = *(const float4*)(h + (size_t)node * OE + lane * 4);
    const float4 wv = *(const float4*)(Wout + lane * 4);
    float v = hv.x * wv.x + hv.y * wv.y + hv.z * wv.z + hv.w * wv.w;
#pragma unroll
    for (int off = 32; off > 0; off >>= 1)
        v += __shfl_down(v, off, 64);
    if (lane == 0) out[node] = v;
}

extern "C" void kernel_launch(void* const* d_in, const int* in_sizes, int n_in,
                              void* d_out, int out_size, void* d_ws, size_t ws_size,
                              hipStream_t stream)
{
    const float* x     = (const float*)d_in[0];
    const float* rbf   = (const float*)d_in[1];
    const int*   idx   = (const int*)d_in[2];
    // d_in[3] = num_nodes scalar (known constant 50000)
    const float* W_rbf = (const float*)d_in[4];
    const float* W_up  = (const float*)d_in[5];
    const float* lw    = (const float*)d_in[6];   // [3,256,256]
    const float* lb    = (const float*)d_in[7];   // [3,256]
    const float* W_out = (const float*)d_in[8];   // [1,256]

    float* h    = (float*)d_ws;                       // NNODES*HID
    float* bufA = h + (size_t)NNODES * HID;           // NNODES*OE
    float* bufB = bufA + (size_t)NNODES * OE;         // NNODES*OE

    hipMemsetAsync(h, 0, (size_t)NNODES * HID * sizeof(float), stream);

    edge_scatter<<<4096, 256, 0, stream>>>(x, rbf, idx, W_rbf, h);

    dim3 grid(OE / 128, (NNODES + 63) / 64);
    gemm_bt<false><<<grid, 256, 0, stream>>>(h, W_up, nullptr, bufA, NNODES, HID);
    gemm_bt<true ><<<grid, 256, 0, stream>>>(bufA, lw + 0 * OE * OE, lb + 0 * OE, bufB, NNODES, OE);
    gemm_bt<true ><<<grid, 256, 0, stream>>>(bufB, lw + 1 * OE * OE, lb + 1 * OE, bufA, NNODES, OE);
    gemm_bt<true ><<<grid, 256, 0, stream>>>(bufA, lw + 2 * OE * OE, lb + 2 * OE, bufB, NNODES, OE);

    out_proj<<<(NNODES + 3) / 4, 256, 0, stream>>>(bufB, W_out, (float*)d_out);
}

// Round 2
// 1754.813 us; speedup vs baseline: 2.1966x; 2.1966x over previous
//
#include <hip/hip_runtime.h>

#define E_EDGES 1600000
#define NNODES  50000
#define HID     128
#define NRAD    6
#define OE      256

// ---------------------------------------------------------------------------
// CSR build stage 1: degree histogram (int atomics, ~32 hits/bin avg)
// ---------------------------------------------------------------------------
__global__ __launch_bounds__(256) void hist_kernel(
    const int* __restrict__ idx, int* __restrict__ deg)
{
    const int e = blockIdx.x * 256 + threadIdx.x;
    if (e < E_EDGES) atomicAdd(&deg[idx[e]], 1);
}

// ---------------------------------------------------------------------------
// CSR build stage 2: exclusive prefix scan of 50000 degrees, one block.
// deg[] is rewritten in-place with the exclusive prefix (becomes the fill
// cursor); row_start[] gets the same values + the E_EDGES sentinel.
// ---------------------------------------------------------------------------
#define SCAN_T 1024
__global__ __launch_bounds__(SCAN_T) void scan_kernel(
    int* __restrict__ deg, int* __restrict__ row_start)
{
    __shared__ int sums[SCAN_T];
    const int t = threadIdx.x;
    const int CH = (NNODES + SCAN_T - 1) / SCAN_T;   // 49
    const int base = t * CH;

    int s = 0;
    for (int i = 0; i < CH; ++i) {
        const int n = base + i;
        if (n < NNODES) s += deg[n];
    }
    sums[t] = s;
    __syncthreads();
    for (int off = 1; off < SCAN_T; off <<= 1) {
        const int v = sums[t];
        const int add = (t >= off) ? sums[t - off] : 0;
        __syncthreads();
        sums[t] = v + add;
        __syncthreads();
    }
    int run = sums[t] - s;                            // exclusive offset
    for (int i = 0; i < CH; ++i) {
        const int n = base + i;
        if (n < NNODES) {
            const int d = deg[n];
            row_start[n] = run;
            deg[n] = run;                             // cursor for fill
            run += d;
        }
    }
    if (t == 0) row_start[NNODES] = E_EDGES;
}

// ---------------------------------------------------------------------------
// CSR build stage 3: scatter edge ids into csr[] via per-node cursors
// ---------------------------------------------------------------------------
__global__ __launch_bounds__(256) void fill_kernel(
    const int* __restrict__ idx, int* __restrict__ cursor,
    int* __restrict__ csr)
{
    const int e = blockIdx.x * 256 + threadIdx.x;
    if (e < E_EDGES) {
        const int p = atomicAdd(&cursor[idx[e]], 1);
        csr[p] = e;
    }
}

// ---------------------------------------------------------------------------
// Gather-reduce: h[n][:] = sum_{e in csr(n)} (W_rbf @ rbf[e]) * x[e][:]
// One 32-lane half-wave per node; lane owns 4 channels (float4).
// Zero atomics; h fully written (no memset needed).
// ---------------------------------------------------------------------------
__global__ __launch_bounds__(256) void gather_kernel(
    const float* __restrict__ x, const float* __restrict__ rbf,
    const int* __restrict__ csr, const int* __restrict__ row_start,
    const float* __restrict__ W_rbf, float* __restrict__ h)
{
    const int tid = threadIdx.x;
    const int c4 = tid & 31;           // channel group: channels c4*4 .. c4*4+3
    const int sub = tid >> 5;          // 0..7 node slot in block
    const int node = blockIdx.x * 8 + sub;

    float w[4][NRAD];
#pragma unroll
    for (int j = 0; j < 4; ++j)
#pragma unroll
        for (int r = 0; r < NRAD; ++r)
            w[j][r] = W_rbf[(c4 * 4 + j) * NRAD + r];

    if (node >= NNODES) return;
    const int beg = row_start[node];
    const int end = row_start[node + 1];

    float4 acc = make_float4(0.f, 0.f, 0.f, 0.f);
    for (int t = beg; t < end; ++t) {
        const int e = csr[t];
        const float* rp = rbf + (size_t)e * NRAD;
        const float r0 = rp[0], r1 = rp[1], r2 = rp[2];
        const float r3 = rp[3], r4 = rp[4], r5 = rp[5];
        const float4 xv = *(const float4*)(x + (size_t)e * HID + c4 * 4);
        const float c0 = w[0][0]*r0 + w[0][1]*r1 + w[0][2]*r2 + w[0][3]*r3 + w[0][4]*r4 + w[0][5]*r5;
        const float c1 = w[1][0]*r0 + w[1][1]*r1 + w[1][2]*r2 + w[1][3]*r3 + w[1][4]*r4 + w[1][5]*r5;
        const float c2 = w[2][0]*r0 + w[2][1]*r1 + w[2][2]*r2 + w[2][3]*r3 + w[2][4]*r4 + w[2][5]*r5;
        const float c3 = w[3][0]*r0 + w[3][1]*r1 + w[3][2]*r2 + w[3][3]*r3 + w[3][4]*r4 + w[3][5]*r5;
        acc.x += c0 * xv.x;
        acc.y += c1 * xv.y;
        acc.z += c2 * xv.z;
        acc.w += c3 * xv.w;
    }
    *(float4*)(h + (size_t)node * HID + c4 * 4) = acc;
}

// ---------------------------------------------------------------------------
// C[M,256] = A[M,K] @ B[256,K]^T (+bias, relu).  Torch Linear convention.
// BM=64, BN=128, BK=16; 256 threads, 4x8 micro-tile per thread.
// ---------------------------------------------------------------------------
template <bool RELU>
__global__ __launch_bounds__(256) void gemm_bt(
    const float* __restrict__ A, const float* __restrict__ B,
    const float* __restrict__ bias, float* __restrict__ C,
    int M, int K)
{
    constexpr int BM = 64, BN = 128, BK = 16;
    __shared__ float As[BK][BM + 4];
    __shared__ float Bs[BK][BN + 4];

    const int tid = threadIdx.x;
    const int m0 = blockIdx.y * BM;
    const int n0 = blockIdx.x * BN;
    const int tm = (tid & 15) * 4;
    const int tn = (tid >> 4) * 8;

    const int lrow = tid >> 2;
    const int lk   = (tid & 3) * 4;

    float acc[4][8] = {};

    for (int k0 = 0; k0 < K; k0 += BK) {
        {
            int row = m0 + lrow;
            row = row < M ? row : M - 1;
            const float4 v = *(const float4*)(A + (size_t)row * K + k0 + lk);
            As[lk + 0][lrow] = v.x; As[lk + 1][lrow] = v.y;
            As[lk + 2][lrow] = v.z; As[lk + 3][lrow] = v.w;
        }
#pragma unroll
        for (int half = 0; half < 2; ++half) {
            const int n = n0 + lrow + half * 64;
            const float4 v = *(const float4*)(B + (size_t)n * K + k0 + lk);
            Bs[lk + 0][lrow + half * 64] = v.x;
            Bs[lk + 1][lrow + half * 64] = v.y;
            Bs[lk + 2][lrow + half * 64] = v.z;
            Bs[lk + 3][lrow + half * 64] = v.w;
        }
        __syncthreads();

#pragma unroll
        for (int k = 0; k < BK; ++k) {
            const float4 a  = *(const float4*)&As[k][tm];
            const float4 b0 = *(const float4*)&Bs[k][tn];
            const float4 b1 = *(const float4*)&Bs[k][tn + 4];
            const float av[4] = {a.x, a.y, a.z, a.w};
            const float bv[8] = {b0.x, b0.y, b0.z, b0.w, b1.x, b1.y, b1.z, b1.w};
#pragma unroll
            for (int r = 0; r < 4; ++r)
#pragma unroll
                for (int c = 0; c < 8; ++c)
                    acc[r][c] += av[r] * bv[c];
        }
        __syncthreads();
    }

    float bvals[8];
#pragma unroll
    for (int c = 0; c < 8; ++c)
        bvals[c] = bias ? bias[n0 + tn + c] : 0.0f;

#pragma unroll
    for (int r = 0; r < 4; ++r) {
        const int m = m0 + tm + r;
        if (m >= M) continue;
        float o[8];
#pragma unroll
        for (int c = 0; c < 8; ++c) {
            float v = acc[r][c] + bvals[c];
            if (RELU) v = fmaxf(v, 0.0f);
            o[c] = v;
        }
        float4* cp = (float4*)(C + (size_t)m * OE + n0 + tn);
        cp[0] = make_float4(o[0], o[1], o[2], o[3]);
        cp[1] = make_float4(o[4], o[5], o[6], o[7]);
    }
}

// ---------------------------------------------------------------------------
// out[n] = dot(h[n][:256], W_out[:256]).  One wave per node, 4 floats/lane.
// ---------------------------------------------------------------------------
__global__ __launch_bounds__(256) void out_proj(
    const float* __restrict__ h, const float* __restrict__ Wout,
    float* __restrict__ out)
{
    const int lane = threadIdx.x & 63;
    const int wave = threadIdx.x >> 6;
    const int node = blockIdx.x * 4 + wave;
    if (node >= NNODES) return;
    const float4 hv = *(const float4*)(h + (size_t)node * OE + lane * 4);
    const float4 wv = *(const float4*)(Wout + lane * 4);
    float v = hv.x * wv.x + hv.y * wv.y + hv.z * wv.z + hv.w * wv.w;
#pragma unroll
    for (int off = 32; off > 0; off >>= 1)
        v += __shfl_down(v, off, 64);
    if (lane == 0) out[node] = v;
}

extern "C" void kernel_launch(void* const* d_in, const int* in_sizes, int n_in,
                              void* d_out, int out_size, void* d_ws, size_t ws_size,
                              hipStream_t stream)
{
    const float* x     = (const float*)d_in[0];
    const float* rbf   = (const float*)d_in[1];
    const int*   idx   = (const int*)d_in[2];
    const float* W_rbf = (const float*)d_in[4];
    const float* W_up  = (const float*)d_in[5];
    const float* lw    = (const float*)d_in[6];   // [3,256,256]
    const float* lb    = (const float*)d_in[7];   // [3,256]
    const float* W_out = (const float*)d_in[8];   // [1,256]

    float* h    = (float*)d_ws;                            // NNODES*HID
    float* bufA = h + (size_t)NNODES * HID;                // NNODES*OE
    float* bufB = bufA + (size_t)NNODES * OE;              // NNODES*OE
    int* cursor    = (int*)(bufB + (size_t)NNODES * OE);   // NNODES (deg -> cursor)
    int* row_start = cursor + NNODES;                      // NNODES+1
    int* csr       = row_start + NNODES + 1;               // E_EDGES

    hipMemsetAsync(cursor, 0, (size_t)NNODES * sizeof(int), stream);

    const int eblocks = (E_EDGES + 255) / 256;
    hist_kernel<<<eblocks, 256, 0, stream>>>(idx, cursor);
    scan_kernel<<<1, SCAN_T, 0, stream>>>(cursor, row_start);
    fill_kernel<<<eblocks, 256, 0, stream>>>(idx, cursor, csr);
    gather_kernel<<<(NNODES + 7) / 8, 256, 0, stream>>>(x, rbf, csr, row_start, W_rbf, h);

    dim3 grid(OE / 128, (NNODES + 63) / 64);
    gemm_bt<false><<<grid, 256, 0, stream>>>(h, W_up, nullptr, bufA, NNODES, HID);
    gemm_bt<true ><<<grid, 256, 0, stream>>>(bufA, lw + 0 * OE * OE, lb + 0 * OE, bufB, NNODES, OE);
    gemm_bt<true ><<<grid, 256, 0, stream>>>(bufB, lw + 1 * OE * OE, lb + 1 * OE, bufA, NNODES, OE);
    gemm_bt<true ><<<grid, 256, 0, stream>>>(bufA, lw + 2 * OE * OE, lb + 2 * OE, bufB, NNODES, OE);

    out_proj<<<(NNODES + 3) / 4, 256, 0, stream>>>(bufB, W_out, (float*)d_out);
}